// Round 11
// baseline (70.080 us; speedup 1.0000x reference)
//
#include <hip/hip_runtime.h>

// out[8,8192] = x[8,8192] @ W^T, W = dequant4(qweight, scale, zero), GROUP=128.
// qweight: one byte value (0..255) per int32, [8192 n][4096 k-bytes], 2 nibbles
// per byte, low nibble = even k.
//
// R11: contiguous-B restage round. R10 diagnosis: B loads scattered as 16 rows
// x 64B per instruction capped the L3 stream at ~3.2 TB/s (vs 6.3 contiguous).
//  - B global loads now CONTIGUOUS: instr i covers rows 4i..4i+3 x 256B runs
//    (lanes 0..15 = consecutive int4s of one row).
//  - Staged through wave-private LDS (8KB/wave) with XOR swizzle
//    slot' = j ^ (row&15): fragment read-back ds_read_b128 has the canonical
//    stride-1 bank profile (~2-way, free). No in-loop barriers (wave-private,
//    DS ops in-order per wave; compiler inserts lgkm waits for aliasing ops).
//  - A slice (16KB bf16 fragments, rows 8..15 zero) built in LDS as R10.
//  - In-loop vmem = ONLY the 8 contiguous B loads per group, 1 group ahead.
//  - C layout (HW-verified): col=lane&15, row=(lane>>4)*4+reg; rows 0..7 real.

typedef __attribute__((ext_vector_type(8))) short bf16x8;
typedef __attribute__((ext_vector_type(4))) float f32x4;

constexpr int Mdim  = 8;
constexpr int N     = 8192;
constexpr int K     = 8192;
constexpr int NG    = 64;           // groups per row
constexpr int KS    = 16;           // K splits
constexpr int KSL   = K / KS;       // 512 k per slice
constexpr int GPS   = KSL / 128;    // 4 groups per slice
constexpr int ROWI4 = K / 8;        // 1024 int4 per weight row
constexpr int SLKK  = KSL / 32;     // 16 A k-blocks per slice

__device__ __forceinline__ float nib_lo(int q) {
    return __int_as_float((q & 15) | 0x4B000000) - 8388608.0f;      // exact
}
__device__ __forceinline__ float nib_hi(int q) {
    return __int_as_float(((q >> 4) & 15) | 0x4B000000) - 8388608.0f;
}
__device__ __forceinline__ int pkbf(float lo, float hi) {           // 2xf32 -> 2xbf16 (RNE)
    int r;
    asm("v_cvt_pk_bf16_f32 %0, %1, %2" : "=v"(r) : "v"(lo), "v"(hi));
    return r;
}

__global__ __launch_bounds__(512, 4) void qmfma_kernel(
    const float* __restrict__ x,      // [8, 8192]
    const int*   __restrict__ qw,     // [8192, 4096]
    const float* __restrict__ scale,  // [8192, 64]
    const float* __restrict__ zero,   // [8192, 64]
    float*       __restrict__ out)    // [8, 8192] pre-zeroed
{
    __shared__ int4 As[SLKK * 64];    // 16KB: A fragments for this k-slice
    __shared__ int4 Bs[8][512];       // 64KB: per-wave B stage (32 rows x 16 slots)

    const int tid  = threadIdx.x;
    const int lane = tid & 63;
    const int wave = tid >> 6;
    const int bid  = blockIdx.x;                  // 512 blocks
    const int ks   = bid >> 5;                    // 0..15
    const int nb   = bid & 31;                    // n-block (256 cols)
    const int c0   = nb * 256 + wave * 32;        // wave's first col (32 rows)
    const int nl0  = c0 + (lane & 15);            // tile0 row / C col
    const int nl1  = nl0 + 16;                    // tile1
    const int kb   = lane >> 4;                   // k-quad 0..3
    const int r    = lane & 15;

    const int g0 = ks * GPS;                      // first group of slice
    const int kq = ks * (KSL / 8);                // int4 offset of slice in a row

    // contiguous B loader: instr i -> row c0 + 4i + (lane>>4), slot lane&15
    const int4* __restrict__ qw4 = reinterpret_cast<const int4*>(qw);
    const int4* __restrict__ bl  =
        qw4 + (size_t)(c0 + (lane >> 4)) * ROWI4 + kq + (lane & 15);

    // ---- group-0 B loads FIRST (latency hides under the A build)
    int4 ln[8];
    #pragma unroll
    for (int i = 0; i < 8; ++i)
        ln[i] = bl[(size_t)(4 * i) * ROWI4];

    float s0 = scale[nl0 * NG + g0], z0 = zero[nl0 * NG + g0];
    float s1 = scale[nl1 * NG + g0], z1 = zero[nl1 * NG + g0];

    // ---- build A-slice in LDS: 1024 fragments, 2 per thread (rows 8..15 zero)
    #pragma unroll
    for (int j = tid; j < SLKK * 64; j += 512) {
        const int ll  = j & 63;
        const int kk  = j >> 6;
        const int row = ll & 15;
        const int k0  = ks * KSL + kk * 32 + (ll >> 4) * 8;
        float4 xa = {0.f, 0.f, 0.f, 0.f}, xb = {0.f, 0.f, 0.f, 0.f};
        if (row < Mdim) {
            const float4* xr = reinterpret_cast<const float4*>(x) + (size_t)row * (K / 4);
            xa = xr[k0 / 4];
            xb = xr[k0 / 4 + 1];
        }
        int4 rr;
        rr.x = pkbf(xa.x, xa.y);
        rr.y = pkbf(xa.z, xa.w);
        rr.z = pkbf(xb.x, xb.y);
        rr.w = pkbf(xb.z, xb.w);
        As[j] = rr;
    }

    // ---- stage group 0 into wave-private Bs (swizzled slots)
    #pragma unroll
    for (int i = 0; i < 8; ++i) {
        const int rl = 4 * i + (lane >> 4);
        Bs[wave][rl * 16 + ((lane & 15) ^ (rl & 15))] = ln[i];
    }
    __syncthreads();                              // A ready (B is wave-private)

    f32x4 acc0 = {0.f, 0.f, 0.f, 0.f};
    f32x4 acc1 = {0.f, 0.f, 0.f, 0.f};
    float s0n = 0.f, z0n = 0.f, s1n = 0.f, z1n = 0.f;

    #pragma unroll 1
    for (int g = 0; g < GPS; ++g) {
        if (g + 1 < GPS) {                        // contiguous prefetch, 1 group ahead
            #pragma unroll
            for (int i = 0; i < 8; ++i)
                ln[i] = bl[(size_t)(4 * i) * ROWI4 + (g + 1) * 16];
            s0n = scale[nl0 * NG + g0 + g + 1]; z0n = zero[nl0 * NG + g0 + g + 1];
            s1n = scale[nl1 * NG + g0 + g + 1]; z1n = zero[nl1 * NG + g0 + g + 1];
        }

        const float cs0 = s0, csz0 = z0 * s0;
        const float cs1 = s1, csz1 = z1 * s1;

        #pragma unroll
        for (int t = 0; t < 4; ++t) {
            const int sl = (t * 4 + kb) ^ r;      // swizzled slot
            const int4 qa = Bs[wave][r * 16 + sl];          // tile0 raw
            const int4 qb = Bs[wave][(16 + r) * 16 + sl];   // tile1 raw

            union { int4 u; bf16x8 v; } A, B0, B1;
            A.u = As[(g * 4 + t) * 64 + lane];

            B0.u.x = pkbf(fmaf(nib_lo(qa.x), cs0, -csz0), fmaf(nib_hi(qa.x), cs0, -csz0));
            B0.u.y = pkbf(fmaf(nib_lo(qa.y), cs0, -csz0), fmaf(nib_hi(qa.y), cs0, -csz0));
            B0.u.z = pkbf(fmaf(nib_lo(qa.z), cs0, -csz0), fmaf(nib_hi(qa.z), cs0, -csz0));
            B0.u.w = pkbf(fmaf(nib_lo(qa.w), cs0, -csz0), fmaf(nib_hi(qa.w), cs0, -csz0));
            B1.u.x = pkbf(fmaf(nib_lo(qb.x), cs1, -csz1), fmaf(nib_hi(qb.x), cs1, -csz1));
            B1.u.y = pkbf(fmaf(nib_lo(qb.y), cs1, -csz1), fmaf(nib_hi(qb.y), cs1, -csz1));
            B1.u.z = pkbf(fmaf(nib_lo(qb.z), cs1, -csz1), fmaf(nib_hi(qb.z), cs1, -csz1));
            B1.u.w = pkbf(fmaf(nib_lo(qb.w), cs1, -csz1), fmaf(nib_hi(qb.w), cs1, -csz1));

            acc0 = __builtin_amdgcn_mfma_f32_16x16x32_bf16(A.v, B0.v, acc0, 0, 0, 0);
            acc1 = __builtin_amdgcn_mfma_f32_16x16x32_bf16(A.v, B1.v, acc1, 0, 0, 0);
        }

        if (g + 1 < GPS) {                        // stage next group (after reads: safe)
            #pragma unroll
            for (int i = 0; i < 8; ++i) {
                const int rl = 4 * i + (lane >> 4);
                Bs[wave][rl * 16 + ((lane & 15) ^ (rl & 15))] = ln[i];
            }
            s0 = s0n; z0 = z0n; s1 = s1n; z1 = z1n;
        }
    }

    // C: col = lane&15, row = kb*4 + i; rows 0..7 real -> kb < 2 stores.
    if (kb < 2) {
        #pragma unroll
        for (int i = 0; i < 4; ++i) {
            const int m = kb * 4 + i;
            atomicAdd(&out[(size_t)m * N + nl0], acc0[i]);
            atomicAdd(&out[(size_t)m * N + nl1], acc1[i]);
        }
    }
}

extern "C" void kernel_launch(void* const* d_in, const int* in_sizes, int n_in,
                              void* d_out, int out_size, void* d_ws, size_t ws_size,
                              hipStream_t stream) {
    const float* x     = (const float*)d_in[0];
    const int*   qw    = (const int*)d_in[1];
    const float* scale = (const float*)d_in[2];
    const float* zero  = (const float*)d_in[3];
    float*       out   = (float*)d_out;

    hipMemsetAsync(out, 0, (size_t)Mdim * N * sizeof(float), stream);
    qmfma_kernel<<<(N / 256) * KS, 512, 0, stream>>>(x, qw, scale, zero, out);
}

// Round 12
// 36.627 us; speedup vs baseline: 1.9134x; 1.9134x over previous
//
#include <hip/hip_runtime.h>

// out[8,8192] = x[8,8192] @ W^T, W = dequant4(qweight, scale, zero), GROUP=128.
// qweight: one byte value (0..255) per int32, [8192 n][4096 k-bytes], 2 nibbles
// per byte, low nibble = even k.
//
// R12: contiguous-B via global_load_lds (no staging registers -> no spills,
// the R11 failure mode).
//  - Per wave: 32 weight rows x 512-k slice (KS=16). Each group (128 k) is
//    staged as 8 global_load_lds_dwordx4 ops: op i covers rows 4i..4i+3 x
//    256B contiguous runs (lanes 0..15 = consecutive int4s of one row).
//  - LDS dest is linear (HW: wave-uniform base + lane*16, m104); the bank
//    swizzle (slot ^= row&15) is applied to the GLOBAL source address and
//    repeated on the ds_read (rule #21) -> read-back is ~2-way (free).
//  - Double-buffered per wave; counted s_waitcnt vmcnt(8) keeps the next
//    group's 8 loads in flight across compute (no drain-to-0 in loop).
//  - In-loop vmcnt stream = ONLY staging loads (scale/zero hoisted to
//    float4 preloads); group loop fully unrolled -> all indices static.
//  - A-slice (16 KB bf16 frags, rows 8..15 zero) built in LDS per block.
//  - C layout (HW-verified): col=lane&15, row=(lane>>4)*4+reg; rows 0..7 real.

typedef __attribute__((ext_vector_type(8))) short bf16x8;
typedef __attribute__((ext_vector_type(4))) float f32x4;

constexpr int Mdim  = 8;
constexpr int N     = 8192;
constexpr int K     = 8192;
constexpr int NG    = 64;           // groups per row
constexpr int KS    = 16;           // K splits
constexpr int KSL   = K / KS;       // 512 k per slice
constexpr int GPS   = KSL / 128;    // 4 groups per slice
constexpr int ROWI4 = K / 8;        // 1024 int4 per weight row
constexpr int SLKK  = KSL / 32;     // 16 A k-blocks per slice

__device__ __forceinline__ float nib_lo(int q) {
    return __int_as_float((q & 15) | 0x4B000000) - 8388608.0f;      // exact
}
__device__ __forceinline__ float nib_hi(int q) {
    return __int_as_float(((q >> 4) & 15) | 0x4B000000) - 8388608.0f;
}
__device__ __forceinline__ int pkbf(float lo, float hi) {           // 2xf32 -> 2xbf16 (RNE)
    int r;
    asm("v_cvt_pk_bf16_f32 %0, %1, %2" : "=v"(r) : "v"(lo), "v"(hi));
    return r;
}

// Stage one 128-k group (32 rows x 16 int4 slots) into wave-private LDS.
// Linear dest; source pre-swizzled so LDS(row, s) = G(row, s ^ (row&15)).
__device__ __forceinline__ void stage_group(const int4* __restrict__ qw4,
                                            int4* dst, int c0, int kq,
                                            int lane, int g) {
    #pragma unroll
    for (int i = 0; i < 8; ++i) {
        const int rl   = 4 * i + (lane >> 4);                 // local row 0..31
        const int gcol = kq + g * 16 + ((lane & 15) ^ (rl & 15));
        const int4* gp = qw4 + (size_t)(c0 + rl) * ROWI4 + gcol;
        __builtin_amdgcn_global_load_lds(
            (const __attribute__((address_space(1))) void*)gp,
            (__attribute__((address_space(3))) void*)(dst + i * 64),
            16, 0, 0);
    }
}

__global__ __launch_bounds__(256, 2) void qmfma_kernel(
    const float* __restrict__ x,      // [8, 8192]
    const int*   __restrict__ qw,     // [8192, 4096]
    const float* __restrict__ scale,  // [8192, 64]
    const float* __restrict__ zero,   // [8192, 64]
    float*       __restrict__ out)    // [8, 8192] pre-zeroed
{
    __shared__ int4 As[SLKK * 64];    // 16KB: A fragments for this k-slice
    __shared__ int4 Bs[4][2][512];    // 64KB: per-wave double-buffered B stage

    const int tid  = threadIdx.x;
    const int lane = tid & 63;
    const int wave = tid >> 6;
    const int bid  = blockIdx.x;                  // 1024 blocks
    const int ks   = bid >> 6;                    // 0..15
    const int nb   = bid & 63;                    // n-block (128 cols)
    const int c0   = nb * 128 + wave * 32;        // wave's first col (32 rows)
    const int nl0  = c0 + (lane & 15);            // tile0 row / C col
    const int nl1  = nl0 + 16;                    // tile1
    const int kb   = lane >> 4;                   // k-quad 0..3
    const int r    = lane & 15;

    const int g0 = ks * GPS;                      // first group of slice
    const int kq = ks * (KSL / 8);                // int4 offset of slice in a row

    const int4* __restrict__ qw4 = reinterpret_cast<const int4*>(qw);
    int4 (*BsW)[512] = Bs[wave];

    // ---- issue group-0 staging FIRST (latency hides under the A build)
    stage_group(qw4, BsW[0], c0, kq, lane, 0);

    // ---- scale/zero for all 4 groups of the slice: one float4 per stream
    const float4 sv0 = *reinterpret_cast<const float4*>(&scale[nl0 * NG + g0]);
    const float4 zv0 = *reinterpret_cast<const float4*>(&zero [nl0 * NG + g0]);
    const float4 sv1 = *reinterpret_cast<const float4*>(&scale[nl1 * NG + g0]);
    const float4 zv1 = *reinterpret_cast<const float4*>(&zero [nl1 * NG + g0]);
    const float sA0[4] = {sv0.x, sv0.y, sv0.z, sv0.w};
    const float zA0[4] = {zv0.x, zv0.y, zv0.z, zv0.w};
    const float sA1[4] = {sv1.x, sv1.y, sv1.z, sv1.w};
    const float zA1[4] = {zv1.x, zv1.y, zv1.z, zv1.w};

    // ---- build A-slice in LDS: 1024 fragments, 4 per thread (rows 8..15 zero)
    #pragma unroll
    for (int jf = tid; jf < SLKK * 64; jf += 256) {
        const int ll  = jf & 63;
        const int kk  = jf >> 6;
        const int row = ll & 15;
        const int k0  = ks * KSL + kk * 32 + (ll >> 4) * 8;
        float4 xa = {0.f, 0.f, 0.f, 0.f}, xb = {0.f, 0.f, 0.f, 0.f};
        if (row < Mdim) {
            const float4* xr = reinterpret_cast<const float4*>(x) + (size_t)row * (K / 4);
            xa = xr[k0 / 4];
            xb = xr[k0 / 4 + 1];
        }
        int4 rr;
        rr.x = pkbf(xa.x, xa.y);
        rr.y = pkbf(xa.z, xa.w);
        rr.z = pkbf(xb.x, xb.y);
        rr.w = pkbf(xb.z, xb.w);
        As[jf] = rr;
    }

    asm volatile("s_waitcnt vmcnt(0)" ::: "memory");   // A x-loads + group-0 DMA done
    __syncthreads();                                   // As visible to all waves

    f32x4 acc0 = {0.f, 0.f, 0.f, 0.f};
    f32x4 acc1 = {0.f, 0.f, 0.f, 0.f};

    #pragma unroll
    for (int g = 0; g < GPS; ++g) {
        const int cur = g & 1;
        if (g + 1 < GPS) {
            // prior ds_reads of the buffer we're about to overwrite are done
            asm volatile("s_waitcnt lgkmcnt(0)" ::: "memory");
            __builtin_amdgcn_sched_barrier(0);
            stage_group(qw4, BsW[cur ^ 1], c0, kq, lane, g + 1);
            // current buffer ready: all but the 8 newest loads complete
            asm volatile("s_waitcnt vmcnt(8)" ::: "memory");
        } else {
            asm volatile("s_waitcnt vmcnt(0)" ::: "memory");
        }
        __builtin_amdgcn_sched_barrier(0);

        const float cs0 = sA0[g], csz0 = zA0[g] * sA0[g];
        const float cs1 = sA1[g], csz1 = zA1[g] * sA1[g];

        #pragma unroll
        for (int t = 0; t < 4; ++t) {
            const int j = t * 4 + kb;
            const int4 qa = BsW[cur][r * 16 + (j ^ r)];          // tile0 raw
            const int4 qb = BsW[cur][(16 + r) * 16 + (j ^ r)];   // tile1 raw

            union { int4 u; bf16x8 v; } A, B0, B1;
            A.u = As[(g * 4 + t) * 64 + lane];

            B0.u.x = pkbf(fmaf(nib_lo(qa.x), cs0, -csz0), fmaf(nib_hi(qa.x), cs0, -csz0));
            B0.u.y = pkbf(fmaf(nib_lo(qa.y), cs0, -csz0), fmaf(nib_hi(qa.y), cs0, -csz0));
            B0.u.z = pkbf(fmaf(nib_lo(qa.z), cs0, -csz0), fmaf(nib_hi(qa.z), cs0, -csz0));
            B0.u.w = pkbf(fmaf(nib_lo(qa.w), cs0, -csz0), fmaf(nib_hi(qa.w), cs0, -csz0));
            B1.u.x = pkbf(fmaf(nib_lo(qb.x), cs1, -csz1), fmaf(nib_hi(qb.x), cs1, -csz1));
            B1.u.y = pkbf(fmaf(nib_lo(qb.y), cs1, -csz1), fmaf(nib_hi(qb.y), cs1, -csz1));
            B1.u.z = pkbf(fmaf(nib_lo(qb.z), cs1, -csz1), fmaf(nib_hi(qb.z), cs1, -csz1));
            B1.u.w = pkbf(fmaf(nib_lo(qb.w), cs1, -csz1), fmaf(nib_hi(qb.w), cs1, -csz1));

            acc0 = __builtin_amdgcn_mfma_f32_16x16x32_bf16(A.v, B0.v, acc0, 0, 0, 0);
            acc1 = __builtin_amdgcn_mfma_f32_16x16x32_bf16(A.v, B1.v, acc1, 0, 0, 0);
        }
    }

    // C: col = lane&15, row = kb*4 + i; rows 0..7 real -> kb < 2 stores.
    if (kb < 2) {
        #pragma unroll
        for (int i = 0; i < 4; ++i) {
            const int m = kb * 4 + i;
            atomicAdd(&out[(size_t)m * N + nl0], acc0[i]);
            atomicAdd(&out[(size_t)m * N + nl1], acc1[i]);
        }
    }
}

extern "C" void kernel_launch(void* const* d_in, const int* in_sizes, int n_in,
                              void* d_out, int out_size, void* d_ws, size_t ws_size,
                              hipStream_t stream) {
    const float* x     = (const float*)d_in[0];
    const int*   qw    = (const int*)d_in[1];
    const float* scale = (const float*)d_in[2];
    const float* zero  = (const float*)d_in[3];
    float*       out   = (float*)d_out;

    hipMemsetAsync(out, 0, (size_t)Mdim * N * sizeof(float), stream);
    qmfma_kernel<<<(N / 128) * KS, 256, 0, stream>>>(x, qw, scale, zero, out);
}